// Round 2
// baseline (276.316 us; speedup 1.0000x reference)
//
#include <hip/hip_runtime.h>
#include <hip/hip_bf16.h>

// QuantizedEmbedding: out[r, d] = code[qw[x[r], d]] * absmax[(x[r]*D + d) >> 12]
//
// Structure: 8 rows per 256-thread block (grid = n_rows/8).
//  - code table (256 fp32) staged in LDS once per block.
//  - 8 row indices prefetched into LDS, then readfirstlane -> scalar base
//    addresses, scalar absmax load (a 1024-elem row chunk always lies inside
//    one 4096-elem absmax block since base % 1024 == 0).
//  - All 8 independent int4 row-chunk loads issued before any is consumed
//    (8x memory-level parallelism vs the 1-load-per-wave R1 version).
//  - Non-temporal float4 stores: out is write-once streaming; keep L2/L3
//    capacity for the gathered qw rows (duplicate row hits).

typedef float v4f __attribute__((ext_vector_type(4)));

#define ROWS_PER_BLOCK 8

__global__ __launch_bounds__(256) void qembed_kernel(
    const int* __restrict__ x,          // [n_rows]
    const int* __restrict__ qw,         // [V, D] int32 codes 0..255
    const float* __restrict__ absmax,   // [n_blocks]
    const float* __restrict__ code,     // [256]
    float* __restrict__ out,            // [n_rows, D]
    int n_rows, int D)
{
    __shared__ float lcode[256];
    __shared__ int lidx[ROWS_PER_BLOCK];

    lcode[threadIdx.x] = code[threadIdx.x];

    const int row0 = blockIdx.x * ROWS_PER_BLOCK;
    if (threadIdx.x < ROWS_PER_BLOCK) {
        int r = row0 + threadIdx.x;
        lidx[threadIdx.x] = (r < n_rows) ? x[r] : 0;
    }
    __syncthreads();

    const int tid = threadIdx.x;

    // D is a multiple of 1024 here (D == 1024); chunk loop kept for generality.
    for (int dbase = 0; dbase < D; dbase += 1024) {
        int4  q[ROWS_PER_BLOCK];
        float am[ROWS_PER_BLOCK];

        // Phase 1: issue all loads (independent -> 8 outstanding 16B loads/lane).
#pragma unroll
        for (int i = 0; i < ROWS_PER_BLOCK; ++i) {
            const int v = __builtin_amdgcn_readfirstlane(lidx[i]);   // wave-uniform
            const long long base = (long long)v * (long long)D + dbase;
            am[i] = absmax[base >> 12];                // scalar (uniform) load
            q[i]  = *reinterpret_cast<const int4*>(qw + base + tid * 4);
        }

        // Phase 2: dequantize + streaming store.
#pragma unroll
        for (int i = 0; i < ROWS_PER_BLOCK; ++i) {
            const int r = row0 + i;
            if (r >= n_rows) break;
            v4f o;
            o.x = lcode[q[i].x & 0xFF] * am[i];
            o.y = lcode[q[i].y & 0xFF] * am[i];
            o.z = lcode[q[i].z & 0xFF] * am[i];
            o.w = lcode[q[i].w & 0xFF] * am[i];
            v4f* dst = reinterpret_cast<v4f*>(out + (long long)r * D + dbase + tid * 4);
            __builtin_nontemporal_store(o, dst);
        }
    }
}

extern "C" void kernel_launch(void* const* d_in, const int* in_sizes, int n_in,
                              void* d_out, int out_size, void* d_ws, size_t ws_size,
                              hipStream_t stream) {
    const int*   x      = (const int*)d_in[0];    // [B*S] indices
    const int*   qw     = (const int*)d_in[1];    // [V*D] int32 codes
    const float* absmax = (const float*)d_in[2];  // [n_blocks]
    const float* code   = (const float*)d_in[3];  // [256]
    float*       out    = (float*)d_out;

    const int n_rows = in_sizes[0];               // 16384
    const int D = out_size / n_rows;              // 1024

    const int grid = (n_rows + ROWS_PER_BLOCK - 1) / ROWS_PER_BLOCK;
    qembed_kernel<<<grid, 256, 0, stream>>>(x, qw, absmax, code, out, n_rows, D);
}